// Round 1
// baseline (1768.148 us; speedup 1.0000x reference)
//
#include <hip/hip_runtime.h>

// Problem constants: B=4, N=5, levels (64,128,256),(128,64,128),(256,32,64)

struct Bilin { int i00, i01, i10, i11; float w00, w01, w10, w11; };

__device__ __forceinline__ Bilin make_bilin(float ix, float iy, int W, int H) {
    float x0f = floorf(ix), y0f = floorf(iy);
    float wx1 = ix - x0f, wy1 = iy - y0f;
    float wx0 = 1.f - wx1, wy0 = 1.f - wy1;
    int x0 = (int)x0f, y0 = (int)y0f;
    int x1 = x0 + 1, y1 = y0 + 1;
    bool vx0 = (x0 >= 0 && x0 < W), vx1 = (x1 >= 0 && x1 < W);
    bool vy0 = (y0 >= 0 && y0 < H), vy1 = (y1 >= 0 && y1 < H);
    int cx0 = min(max(x0, 0), W - 1), cx1 = min(max(x1, 0), W - 1);
    int cy0 = min(max(y0, 0), H - 1), cy1 = min(max(y1, 0), H - 1);
    Bilin b;
    b.i00 = cy0 * W + cx0; b.i01 = cy0 * W + cx1;
    b.i10 = cy1 * W + cx0; b.i11 = cy1 * W + cx1;
    b.w00 = (vx0 && vy0) ? wx0 * wy0 : 0.f;
    b.w01 = (vx1 && vy0) ? wx1 * wy0 : 0.f;
    b.w10 = (vx0 && vy1) ? wx0 * wy1 : 0.f;
    b.w11 = (vx1 && vy1) ? wx1 * wy1 : 0.f;
    return b;
}

// Affine warp (align_corners=True). Thread = (img, 16-chan group, h, w).
__global__ __launch_bounds__(256) void warp_kernel(
    const float* __restrict__ src, const float* __restrict__ tmat,
    float* __restrict__ dst, int C, int H, int W)
{
    int idx = blockIdx.x * 256 + threadIdx.x;
    int CGn = C >> 4;
    int HW = H * W;
    int total = 20 * CGn * HW;
    if (idx >= total) return;
    int w   = idx % W;
    int h   = (idx / W) % H;
    int cg  = (idx / HW) % CGn;
    int img = idx / (HW * CGn);
    int b = img / 5, n = img % 5;
    const float* th = tmat + (b * 25 + n) * 6;  // pairwise_t[b,0,n]
    float gx = -1.f + 2.f * w / (float)(W - 1);
    float gy = -1.f + 2.f * h / (float)(H - 1);
    float tx = th[0] * gx + th[1] * gy + th[2];
    float ty = th[3] * gx + th[4] * gy + th[5];
    float ix = (tx + 1.f) * 0.5f * (W - 1);
    float iy = (ty + 1.f) * 0.5f * (H - 1);
    Bilin bl = make_bilin(ix, iy, W, H);
    const float* im = src + ((size_t)img * C + cg * 16) * HW;
    float* op = dst + ((size_t)img * C + cg * 16) * HW + h * W + w;
    #pragma unroll 4
    for (int c = 0; c < 16; ++c) {
        const float* pl = im + c * HW;
        op[c * HW] = pl[bl.i00] * bl.w00 + pl[bl.i01] * bl.w01 +
                     pl[bl.i10] * bl.w10 + pl[bl.i11] * bl.w11;
    }
}

// Per-(image,channel) mean / rsqrt(var+eps) over H*W.
__global__ __launch_bounds__(256) void stats_kernel(
    const float* __restrict__ x, float* __restrict__ stats, int HW)
{
    int pc = blockIdx.x;
    const float* p = x + (size_t)pc * HW;
    float s = 0.f, s2 = 0.f;
    for (int i = threadIdx.x; i < HW; i += 256) {
        float v = p[i];
        s += v; s2 += v * v;
    }
    __shared__ float ss[256], sq[256];
    ss[threadIdx.x] = s; sq[threadIdx.x] = s2;
    __syncthreads();
    for (int o = 128; o > 0; o >>= 1) {
        if (threadIdx.x < o) {
            ss[threadIdx.x] += ss[threadIdx.x + o];
            sq[threadIdx.x] += sq[threadIdx.x + o];
        }
        __syncthreads();
    }
    if (threadIdx.x == 0) {
        float m = ss[0] / HW;
        float var = sq[0] / HW - m * m;
        stats[pc * 2]     = m;
        stats[pc * 2 + 1] = rsqrtf(var + 1e-5f);
    }
}

// Direct 3x3 conv, pad=1, on 16 images of 128x256.
// GATHER: input is the virtual concat [warped0[b,0], warped0[b,j]] (128 ch).
// stats != nullptr: apply instance-norm + leaky to input values (pad stays 0).
// Block: 8x32 output tile, all COUT channels. Thread: 4 px (along W) x COUT/4.
template<int CIN, int COUT, bool GATHER>
__global__ __launch_bounds__(256) void conv3x3_kernel(
    const float* __restrict__ src, const float* __restrict__ wgt,
    const float* __restrict__ bias, const float* __restrict__ stats,
    float* __restrict__ dst)
{
    constexpr int H = 128, W = 256, HW = H * W;
    constexpr int CHUNK = 16;
    constexpr int OCP = COUT / 4;
    __shared__ float s_in[CHUNK][10][34];
    __shared__ float s_w[COUT][CHUNK][9];
    int tid = threadIdx.x;
    int bi = blockIdx.x;
    int p = bi >> 7;            // image 0..15
    int rem = bi & 127;
    int h_base = (rem >> 3) * 8;
    int w_base = (rem & 7) * 32;
    int cg = tid >> 6;          // cout group 0..3
    int sg = tid & 63;
    int r  = sg >> 3;           // row in tile 0..7
    int cb = (sg & 7) * 4;      // col base in tile

    float acc[4][OCP];
    #pragma unroll
    for (int i = 0; i < 4; ++i)
        #pragma unroll
        for (int o = 0; o < OCP; ++o) acc[i][o] = 0.f;

    for (int ci = 0; ci < CIN / CHUNK; ++ci) {
        if (ci) __syncthreads();
        // stage input tile (with halo, zero-padded)
        for (int t = tid; t < CHUNK * 10 * 34; t += 256) {
            int c = t / 340;
            int r2 = t % 340;
            int row = r2 / 34, col = r2 % 34;
            int gy = h_base + row - 1, gxx = w_base + col - 1;
            float v = 0.f;
            if (gy >= 0 && gy < H && gxx >= 0 && gxx < W) {
                int cglob = ci * CHUNK + c;
                const float* plane;
                if (GATHER) {
                    int bb = p >> 2, jm = p & 3;
                    int n = (cglob < 64) ? 0 : (jm + 1);
                    plane = src + ((size_t)(bb * 5 + n) * 64 + (cglob & 63)) * HW;
                } else {
                    plane = src + ((size_t)p * CIN + cglob) * HW;
                }
                v = plane[gy * W + gxx];
                if (stats) {
                    float m  = stats[(p * CIN + cglob) * 2];
                    float rs = stats[(p * CIN + cglob) * 2 + 1];
                    v = (v - m) * rs;
                    v = v >= 0.f ? v : 0.01f * v;
                }
            }
            s_in[c][row][col] = v;
        }
        // stage weights for this cin chunk
        for (int t = tid; t < COUT * CHUNK * 9; t += 256) {
            int o = t / (CHUNK * 9);
            int r2 = t % (CHUNK * 9);
            s_w[o][r2 / 9][r2 % 9] = wgt[((size_t)o * CIN + ci * CHUNK + r2 / 9) * 9 + (r2 % 9)];
        }
        __syncthreads();
        // compute
        for (int c = 0; c < CHUNK; ++c) {
            #pragma unroll
            for (int dy = 0; dy < 3; ++dy) {
                #pragma unroll
                for (int dx = 0; dx < 3; ++dx) {
                    float i0 = s_in[c][r + dy][cb + dx + 0];
                    float i1 = s_in[c][r + dy][cb + dx + 1];
                    float i2 = s_in[c][r + dy][cb + dx + 2];
                    float i3 = s_in[c][r + dy][cb + dx + 3];
                    #pragma unroll
                    for (int o = 0; o < OCP; ++o) {
                        float wv = s_w[cg * OCP + o][c][dy * 3 + dx];
                        acc[0][o] = fmaf(i0, wv, acc[0][o]);
                        acc[1][o] = fmaf(i1, wv, acc[1][o]);
                        acc[2][o] = fmaf(i2, wv, acc[2][o]);
                        acc[3][o] = fmaf(i3, wv, acc[3][o]);
                    }
                }
            }
        }
    }
    int hh = h_base + r, ww = w_base + cb;
    #pragma unroll
    for (int o = 0; o < OCP; ++o) {
        int oc = cg * OCP + o;
        float bv = bias[oc];
        float4 v = make_float4(acc[0][o] + bv, acc[1][o] + bv,
                               acc[2][o] + bv, acc[3][o] + bv);
        *reinterpret_cast<float4*>(dst + (((size_t)p * COUT + oc) * H + hh) * W + ww) = v;
    }
}

// 1x1 conv with fused instance-norm+leaky on input.
template<int CIN, int COUT>
__global__ __launch_bounds__(256) void conv1x1_kernel(
    const float* __restrict__ src, const float* __restrict__ wgt,
    const float* __restrict__ bias, const float* __restrict__ stats,
    float* __restrict__ dst)
{
    constexpr int HW = 128 * 256;
    __shared__ float s_w[COUT * CIN];
    __shared__ float s_b[COUT];
    int tid = threadIdx.x;
    for (int t = tid; t < COUT * CIN; t += 256) s_w[t] = wgt[t];
    if (tid < COUT) s_b[tid] = bias[tid];
    __syncthreads();
    int p  = blockIdx.x >> 7;                 // 128 blocks per image
    int px = ((blockIdx.x & 127) << 8) + tid;
    float in[CIN];
    #pragma unroll
    for (int c = 0; c < CIN; ++c) {
        float v  = src[((size_t)p * CIN + c) * HW + px];
        float m  = stats[(p * CIN + c) * 2];
        float rs = stats[(p * CIN + c) * 2 + 1];
        v = (v - m) * rs;
        in[c] = v >= 0.f ? v : 0.01f * v;
    }
    #pragma unroll
    for (int o = 0; o < COUT; ++o) {
        float s = s_b[o];
        #pragma unroll
        for (int c = 0; c < CIN; ++c) s = fmaf(in[c], s_w[o * CIN + c], s);
        dst[((size_t)p * COUT + o) * HW + px] = s;
    }
}

// Deformable sample of the 4 neighbors + max with ego warped feature.
// grid buffer G is conv4 NCHW output; reference's reshape (16,2,128,256)->
// (16,128,256,2) is a flat reinterpretation: G[p*65536 + (h0*256+w0)*2 + k].
__global__ __launch_bounds__(256) void fuse_kernel(
    const float* __restrict__ warped, const float* __restrict__ grid,
    float* __restrict__ out, int C, int Hs, int Ws, int shift)
{
    int idx = blockIdx.x * 256 + threadIdx.x;
    int CGn = C >> 4;
    int HW = Hs * Ws;
    int total = 4 * CGn * HW;
    if (idx >= total) return;
    int w  = idx % Ws;
    int h  = (idx / Ws) % Hs;
    int cg = (idx / HW) % CGn;
    int b  = idx / (HW * CGn);
    int h0 = h << shift, w0 = w << shift;
    float bx = (w0 + 0.5f) * (2.f / 256.f) - 1.f;
    float by = (h0 + 0.5f) * (2.f / 128.f) - 1.f;
    Bilin bl[4];
    #pragma unroll
    for (int j = 0; j < 4; ++j) {
        int p = b * 4 + j;
        const float* g = grid + (size_t)p * 65536 + (size_t)(h0 * 256 + w0) * 2;
        float fx = g[0] + bx;
        float fy = g[1] + by;
        float ix = ((fx + 1.f) * Ws - 1.f) * 0.5f;   // align_corners=False
        float iy = ((fy + 1.f) * Hs - 1.f) * 0.5f;
        bl[j] = make_bilin(ix, iy, Ws, Hs);
    }
    size_t egoOff = ((size_t)(b * 5) * C + cg * 16) * HW;
    float* op = out + ((size_t)b * C + cg * 16) * HW + h * Ws + w;
    for (int c = 0; c < 16; ++c) {
        float m = warped[egoOff + (size_t)c * HW + h * Ws + w];
        #pragma unroll
        for (int j = 0; j < 4; ++j) {
            const float* pl = warped + ((size_t)(b * 5 + 1 + j) * C + cg * 16 + c) * HW;
            float s = pl[bl[j].i00] * bl[j].w00 + pl[bl[j].i01] * bl[j].w01 +
                      pl[bl[j].i10] * bl[j].w10 + pl[bl[j].i11] * bl[j].w11;
            m = fmaxf(m, s);
        }
        op[(size_t)c * HW] = m;
    }
}

extern "C" void kernel_launch(void* const* d_in, const int* in_sizes, int n_in,
                              void* d_out, int out_size, void* d_ws, size_t ws_size,
                              hipStream_t stream)
{
    const float* feat0 = (const float*)d_in[0];
    const float* feat1 = (const float*)d_in[1];
    const float* feat2 = (const float*)d_in[2];
    const float* tmat  = (const float*)d_in[3];
    // d_in[4] = record_len (unused: always N)
    const float* w1 = (const float*)d_in[5];
    const float* b1 = (const float*)d_in[6];
    const float* w2 = (const float*)d_in[7];
    const float* b2 = (const float*)d_in[8];
    const float* w3 = (const float*)d_in[9];
    const float* b3 = (const float*)d_in[10];
    const float* w4 = (const float*)d_in[11];
    const float* b4 = (const float*)d_in[12];
    float* out = (float*)d_out;
    float* ws  = (float*)d_ws;

    // workspace layout (floats)
    const size_t nW0 = 41943040;  // 20*64*128*256
    const size_t nW1 = 20971520;  // 20*128*64*128
    const size_t nW2 = 10485760;  // 20*256*32*64
    const size_t nX1 = 16777216;  // 16*32*128*256
    const size_t nX2 = 8388608;   // 16*16*128*256
    const size_t nX3 = 4194304;   // 16*8*128*256
    const size_t nG  = 2097152;   // 16*2*128*256
    const size_t needed = (nW0 + nW1 + nW2 + nX1 + nX2 + nX3 + nG + 2048) * 4;
    if (ws_size < needed) return;  // refuse to corrupt memory

    float* W0 = ws;
    float* W1 = W0 + nW0;
    float* W2 = W1 + nW1;
    float* X1 = W2 + nW2;
    float* X2 = X1 + nX1;
    float* X3 = X2 + nX2;
    float* G  = X3 + nX3;
    float* S  = G  + nG;   // stats: S1@0 (1024), S2@1024 (512), S3@1536 (256)

    // 1. affine warps (align_corners=True)
    warp_kernel<<<10240, 256, 0, stream>>>(feat0, tmat, W0, 64, 128, 256);
    warp_kernel<<<5120,  256, 0, stream>>>(feat1, tmat, W1, 128, 64, 128);
    warp_kernel<<<2560,  256, 0, stream>>>(feat2, tmat, W2, 256, 32, 64);

    // 2. offset CNN
    conv3x3_kernel<128, 32, true ><<<2048, 256, 0, stream>>>(W0, w1, b1, nullptr, X1);
    stats_kernel<<<512, 256, 0, stream>>>(X1, S, 32768);
    conv3x3_kernel<32, 16, false><<<2048, 256, 0, stream>>>(X1, w2, b2, S, X2);
    stats_kernel<<<256, 256, 0, stream>>>(X2, S + 1024, 32768);
    conv1x1_kernel<16, 8><<<2048, 256, 0, stream>>>(X2, w3, b3, S + 1024, X3);
    stats_kernel<<<128, 256, 0, stream>>>(X3, S + 1536, 32768);
    conv1x1_kernel<8, 2><<<2048, 256, 0, stream>>>(X3, w4, b4, S + 1536, G);

    // 3. deform + max fusion per level
    fuse_kernel<<<2048, 256, 0, stream>>>(W0, G, out,            64, 128, 256, 0);
    fuse_kernel<<<1024, 256, 0, stream>>>(W1, G, out + 8388608, 128,  64, 128, 1);
    fuse_kernel<<<512,  256, 0, stream>>>(W2, G, out + 12582912, 256, 32,  64, 2);
}

// Round 2
// 1504.176 us; speedup vs baseline: 1.1755x; 1.1755x over previous
//
#include <hip/hip_runtime.h>

// Problem constants: B=4, N=5, levels (64,128,256),(128,64,128),(256,32,64)

struct Bilin { int i00, i01, i10, i11; float w00, w01, w10, w11; };

__device__ __forceinline__ Bilin make_bilin(float ix, float iy, int W, int H) {
    float x0f = floorf(ix), y0f = floorf(iy);
    float wx1 = ix - x0f, wy1 = iy - y0f;
    float wx0 = 1.f - wx1, wy0 = 1.f - wy1;
    int x0 = (int)x0f, y0 = (int)y0f;
    int x1 = x0 + 1, y1 = y0 + 1;
    bool vx0 = (x0 >= 0 && x0 < W), vx1 = (x1 >= 0 && x1 < W);
    bool vy0 = (y0 >= 0 && y0 < H), vy1 = (y1 >= 0 && y1 < H);
    int cx0 = min(max(x0, 0), W - 1), cx1 = min(max(x1, 0), W - 1);
    int cy0 = min(max(y0, 0), H - 1), cy1 = min(max(y1, 0), H - 1);
    Bilin b;
    b.i00 = cy0 * W + cx0; b.i01 = cy0 * W + cx1;
    b.i10 = cy1 * W + cx0; b.i11 = cy1 * W + cx1;
    b.w00 = (vx0 && vy0) ? wx0 * wy0 : 0.f;
    b.w01 = (vx1 && vy0) ? wx1 * wy0 : 0.f;
    b.w10 = (vx0 && vy1) ? wx0 * wy1 : 0.f;
    b.w11 = (vx1 && vy1) ? wx1 * wy1 : 0.f;
    return b;
}

// Affine warp (align_corners=True). Thread = (img, 16-chan group, h, w).
__global__ __launch_bounds__(256) void warp_kernel(
    const float* __restrict__ src, const float* __restrict__ tmat,
    float* __restrict__ dst, int C, int H, int W)
{
    int idx = blockIdx.x * 256 + threadIdx.x;
    int CGn = C >> 4;
    int HW = H * W;
    int total = 20 * CGn * HW;
    if (idx >= total) return;
    int w   = idx % W;
    int h   = (idx / W) % H;
    int cg  = (idx / HW) % CGn;
    int img = idx / (HW * CGn);
    int b = img / 5, n = img % 5;
    const float* th = tmat + (b * 25 + n) * 6;  // pairwise_t[b,0,n]
    float gx = -1.f + 2.f * w / (float)(W - 1);
    float gy = -1.f + 2.f * h / (float)(H - 1);
    float tx = th[0] * gx + th[1] * gy + th[2];
    float ty = th[3] * gx + th[4] * gy + th[5];
    float ix = (tx + 1.f) * 0.5f * (W - 1);
    float iy = (ty + 1.f) * 0.5f * (H - 1);
    Bilin bl = make_bilin(ix, iy, W, H);
    const float* im = src + ((size_t)img * C + cg * 16) * HW;
    float* op = dst + ((size_t)img * C + cg * 16) * HW + h * W + w;
    #pragma unroll 4
    for (int c = 0; c < 16; ++c) {
        const float* pl = im + c * HW;
        op[c * HW] = pl[bl.i00] * bl.w00 + pl[bl.i01] * bl.w01 +
                     pl[bl.i10] * bl.w10 + pl[bl.i11] * bl.w11;
    }
}

// Per-(image,channel) mean / rsqrt(var+eps) over H*W.
__global__ __launch_bounds__(256) void stats_kernel(
    const float* __restrict__ x, float* __restrict__ stats, int HW)
{
    int pc = blockIdx.x;
    const float* p = x + (size_t)pc * HW;
    float s = 0.f, s2 = 0.f;
    for (int i = threadIdx.x; i < HW; i += 256) {
        float v = p[i];
        s += v; s2 += v * v;
    }
    __shared__ float ss[256], sq[256];
    ss[threadIdx.x] = s; sq[threadIdx.x] = s2;
    __syncthreads();
    for (int o = 128; o > 0; o >>= 1) {
        if (threadIdx.x < o) {
            ss[threadIdx.x] += ss[threadIdx.x + o];
            sq[threadIdx.x] += sq[threadIdx.x + o];
        }
        __syncthreads();
    }
    if (threadIdx.x == 0) {
        float m = ss[0] / HW;
        float var = sq[0] / HW - m * m;
        stats[pc * 2]     = m;
        stats[pc * 2 + 1] = rsqrtf(var + 1e-5f);
    }
}

// Direct 3x3 conv v2, pad=1, H=128 W=256.
// Tile: 8 rows x 64 cols per block; thread = 8 px (along W) x OCP couts.
// SRC: 0 = plain NCHW input (nimg imgs, CIN ch)
//      1 = ego    : img p in 0..3  -> warped0 plane (p*5 + 0,   ch cglob)
//      2 = neigh  : img p in 0..15 -> warped0 plane (b*5+1+jm,  ch cglob)
// WSTRIDE: cin stride of the weight tensor (conv1 full tensor = 128).
// INIT: accumulator initialized from `init` (ego partial sums, per batch).
// NORM: apply instance-norm + leaky (from `stats`) to inputs at staging.
// SRC==1 writes RAW sums (no bias); bias applied by the consumer (SRC==2).
template<int CIN, int COUT, int WSTRIDE, int SRC, bool INIT, bool NORM>
__global__ __launch_bounds__(256) void conv3x3v2(
    const float* __restrict__ src, const float* __restrict__ wgt,
    const float* __restrict__ bias, const float* __restrict__ stats,
    const float* __restrict__ init, float* __restrict__ dst)
{
    constexpr int H = 128, W = 256, HW = H * W;
    constexpr int CHUNK = 8;
    constexpr int OCP = COUT / 4;
    constexpr int PW = 68;                       // padded row pitch (floats)
    __shared__ __align__(16) float s_in[CHUNK][10][PW];
    __shared__ __align__(16) float s_w[CHUNK * 9 * COUT];

    int tid = threadIdx.x;
    int bi  = blockIdx.x;
    int p   = bi >> 6;                 // image index
    int rem = bi & 63;
    int h_base = (rem >> 2) * 8;
    int w_base = (rem & 3) * 64;
    int cg = tid >> 6;                 // cout group
    int sg = tid & 63;
    int r  = sg >> 3;                  // row in tile 0..7
    int cw = (sg & 7) * 8;             // col base in tile (mult of 8)

    float acc[OCP][8];
    #pragma unroll
    for (int o = 0; o < OCP; ++o)
        #pragma unroll
        for (int i = 0; i < 8; ++i) acc[o][i] = 0.f;

    for (int ci = 0; ci < CIN / CHUNK; ++ci) {
        if (ci) __syncthreads();
        // ---- stage input tile (10 x 66 with halo, zero-padded) ----
        for (int t = tid; t < CHUNK * 10 * 66; t += 256) {
            int c   = t / 660;
            int r2  = t % 660;
            int row = r2 / 66, col = r2 % 66;
            int gy = h_base + row - 1, gxx = w_base + col - 1;
            float v = 0.f;
            if (gy >= 0 && gy < H && gxx >= 0 && gxx < W) {
                int cglob = ci * CHUNK + c;
                const float* plane;
                if (SRC == 1) {
                    plane = src + ((size_t)(p * 5) * 64 + cglob) * HW;
                } else if (SRC == 2) {
                    int bb = p >> 2, jm = p & 3;
                    plane = src + ((size_t)(bb * 5 + 1 + jm) * 64 + cglob) * HW;
                } else {
                    plane = src + ((size_t)p * CIN + cglob) * HW;
                }
                v = plane[gy * W + gxx];
                if (NORM) {
                    float m  = stats[(p * CIN + cglob) * 2];
                    float rs = stats[(p * CIN + cglob) * 2 + 1];
                    v = (v - m) * rs;
                    v = v >= 0.f ? v : 0.01f * v;
                }
            }
            s_in[c][row][col] = v;
        }
        // ---- stage weights: layout [c][pos][COUT] ----
        for (int t = tid; t < CHUNK * 9 * COUT; t += 256) {
            int c   = t / (9 * COUT);
            int pos = (t / COUT) % 9;
            int o   = t % COUT;
            s_w[(c * 9 + pos) * COUT + o] =
                wgt[((size_t)o * WSTRIDE + ci * CHUNK + c) * 9 + pos];
        }
        __syncthreads();
        // ---- compute ----
        #pragma unroll 1
        for (int c = 0; c < CHUNK; ++c) {
            float in[3][10];
            #pragma unroll
            for (int dy = 0; dy < 3; ++dy) {
                const float* rp = &s_in[c][r + dy][cw];
                float4 a = *reinterpret_cast<const float4*>(rp);
                float4 b = *reinterpret_cast<const float4*>(rp + 4);
                float2 e = *reinterpret_cast<const float2*>(rp + 8);
                in[dy][0] = a.x; in[dy][1] = a.y; in[dy][2] = a.z; in[dy][3] = a.w;
                in[dy][4] = b.x; in[dy][5] = b.y; in[dy][6] = b.z; in[dy][7] = b.w;
                in[dy][8] = e.x; in[dy][9] = e.y;
            }
            const float* wp = &s_w[c * 9 * COUT + cg * OCP];
            #pragma unroll
            for (int dy = 0; dy < 3; ++dy) {
                #pragma unroll
                for (int dx = 0; dx < 3; ++dx) {
                    float wv[OCP];
                    #pragma unroll
                    for (int o = 0; o < OCP; o += 4) {
                        float4 wq = *reinterpret_cast<const float4*>(wp + (dy * 3 + dx) * COUT + o);
                        wv[o] = wq.x; wv[o + 1] = wq.y; wv[o + 2] = wq.z; wv[o + 3] = wq.w;
                    }
                    #pragma unroll
                    for (int o = 0; o < OCP; ++o)
                        #pragma unroll
                        for (int px = 0; px < 8; ++px)
                            acc[o][px] = fmaf(in[dy][dx + px], wv[o], acc[o][px]);
                }
            }
        }
    }
    // ---- epilogue ----
    int hh = h_base + r, ww = w_base + cw;
    #pragma unroll
    for (int o = 0; o < OCP; ++o) {
        int oc = cg * OCP + o;
        float bv = (SRC == 1) ? 0.f : bias[oc];
        float add[8];
        #pragma unroll
        for (int i = 0; i < 8; ++i) add[i] = bv;
        if (INIT) {
            int bb = (SRC == 2) ? (p >> 2) : p;
            const float* ip = init + ((size_t)bb * COUT + oc) * HW + hh * W + ww;
            float4 e0 = *reinterpret_cast<const float4*>(ip);
            float4 e1 = *reinterpret_cast<const float4*>(ip + 4);
            add[0] += e0.x; add[1] += e0.y; add[2] += e0.z; add[3] += e0.w;
            add[4] += e1.x; add[5] += e1.y; add[6] += e1.z; add[7] += e1.w;
        }
        float* op = dst + (((size_t)p * COUT + oc) * H + hh) * W + ww;
        float4 v0 = make_float4(acc[o][0] + add[0], acc[o][1] + add[1],
                                acc[o][2] + add[2], acc[o][3] + add[3]);
        float4 v1 = make_float4(acc[o][4] + add[4], acc[o][5] + add[5],
                                acc[o][6] + add[6], acc[o][7] + add[7]);
        *reinterpret_cast<float4*>(op)     = v0;
        *reinterpret_cast<float4*>(op + 4) = v1;
    }
}

// 1x1 conv with fused instance-norm+leaky on input.
template<int CIN, int COUT>
__global__ __launch_bounds__(256) void conv1x1_kernel(
    const float* __restrict__ src, const float* __restrict__ wgt,
    const float* __restrict__ bias, const float* __restrict__ stats,
    float* __restrict__ dst)
{
    constexpr int HW = 128 * 256;
    __shared__ float s_w[COUT * CIN];
    __shared__ float s_b[COUT];
    int tid = threadIdx.x;
    for (int t = tid; t < COUT * CIN; t += 256) s_w[t] = wgt[t];
    if (tid < COUT) s_b[tid] = bias[tid];
    __syncthreads();
    int p  = blockIdx.x >> 7;                 // 128 blocks per image
    int px = ((blockIdx.x & 127) << 8) + tid;
    float in[CIN];
    #pragma unroll
    for (int c = 0; c < CIN; ++c) {
        float v  = src[((size_t)p * CIN + c) * HW + px];
        float m  = stats[(p * CIN + c) * 2];
        float rs = stats[(p * CIN + c) * 2 + 1];
        v = (v - m) * rs;
        in[c] = v >= 0.f ? v : 0.01f * v;
    }
    #pragma unroll
    for (int o = 0; o < COUT; ++o) {
        float s = s_b[o];
        #pragma unroll
        for (int c = 0; c < CIN; ++c) s = fmaf(in[c], s_w[o * CIN + c], s);
        dst[((size_t)p * COUT + o) * HW + px] = s;
    }
}

// Deformable sample of the 4 neighbors + max with ego warped feature.
// grid buffer G is conv4 NCHW output; reference's reshape (16,2,128,256)->
// (16,128,256,2) is a flat reinterpretation: G[p*65536 + (h0*256+w0)*2 + k].
__global__ __launch_bounds__(256) void fuse_kernel(
    const float* __restrict__ warped, const float* __restrict__ grid,
    float* __restrict__ out, int C, int Hs, int Ws, int shift)
{
    int idx = blockIdx.x * 256 + threadIdx.x;
    int CGn = C >> 4;
    int HW = Hs * Ws;
    int total = 4 * CGn * HW;
    if (idx >= total) return;
    int w  = idx % Ws;
    int h  = (idx / Ws) % Hs;
    int cg = (idx / HW) % CGn;
    int b  = idx / (HW * CGn);
    int h0 = h << shift, w0 = w << shift;
    float bx = (w0 + 0.5f) * (2.f / 256.f) - 1.f;
    float by = (h0 + 0.5f) * (2.f / 128.f) - 1.f;
    Bilin bl[4];
    #pragma unroll
    for (int j = 0; j < 4; ++j) {
        int p = b * 4 + j;
        const float* g = grid + (size_t)p * 65536 + (size_t)(h0 * 256 + w0) * 2;
        float fx = g[0] + bx;
        float fy = g[1] + by;
        float ix = ((fx + 1.f) * Ws - 1.f) * 0.5f;   // align_corners=False
        float iy = ((fy + 1.f) * Hs - 1.f) * 0.5f;
        bl[j] = make_bilin(ix, iy, Ws, Hs);
    }
    size_t egoOff = ((size_t)(b * 5) * C + cg * 16) * HW;
    float* op = out + ((size_t)b * C + cg * 16) * HW + h * Ws + w;
    for (int c = 0; c < 16; ++c) {
        float m = warped[egoOff + (size_t)c * HW + h * Ws + w];
        #pragma unroll
        for (int j = 0; j < 4; ++j) {
            const float* pl = warped + ((size_t)(b * 5 + 1 + j) * C + cg * 16 + c) * HW;
            float s = pl[bl[j].i00] * bl[j].w00 + pl[bl[j].i01] * bl[j].w01 +
                      pl[bl[j].i10] * bl[j].w10 + pl[bl[j].i11] * bl[j].w11;
            m = fmaxf(m, s);
        }
        op[(size_t)c * HW] = m;
    }
}

extern "C" void kernel_launch(void* const* d_in, const int* in_sizes, int n_in,
                              void* d_out, int out_size, void* d_ws, size_t ws_size,
                              hipStream_t stream)
{
    const float* feat0 = (const float*)d_in[0];
    const float* feat1 = (const float*)d_in[1];
    const float* feat2 = (const float*)d_in[2];
    const float* tmat  = (const float*)d_in[3];
    // d_in[4] = record_len (unused: always N)
    const float* w1 = (const float*)d_in[5];
    const float* b1 = (const float*)d_in[6];
    const float* w2 = (const float*)d_in[7];
    const float* b2 = (const float*)d_in[8];
    const float* w3 = (const float*)d_in[9];
    const float* b3 = (const float*)d_in[10];
    const float* w4 = (const float*)d_in[11];
    const float* b4 = (const float*)d_in[12];
    float* out = (float*)d_out;
    float* ws  = (float*)d_ws;

    // workspace layout (floats)
    const size_t nW0 = 41943040;  // 20*64*128*256
    const size_t nW1 = 20971520;  // 20*128*64*128
    const size_t nW2 = 10485760;  // 20*256*32*64
    const size_t nX1 = 16777216;  // 16*32*128*256
    const size_t nX2 = 8388608;   // 16*16*128*256
    const size_t nX3 = 4194304;   // 16*8*128*256
    const size_t nG  = 2097152;   // 16*2*128*256
    const size_t needed = (nW0 + nW1 + nW2 + nX1 + nX2 + nX3 + nG + 2048) * 4;
    if (ws_size < needed) return;  // refuse to corrupt memory

    float* W0 = ws;
    float* W1 = W0 + nW0;
    float* W2 = W1 + nW1;
    float* X1 = W2 + nW2;
    float* X2 = X1 + nX1;
    float* X3 = X2 + nX2;
    float* G  = X3 + nX3;
    float* S  = G  + nG;   // stats: S1@0 (1024), S2@1024 (512), S3@1536 (256)
    float* E  = X2;        // ego partial sums (4*32*32768 = 4.2M floats) — X2 is
                           // dead until conv2 writes it, so reuse the space.

    // 1. affine warps (align_corners=True)
    warp_kernel<<<10240, 256, 0, stream>>>(feat0, tmat, W0, 64, 128, 256);
    warp_kernel<<<5120,  256, 0, stream>>>(feat1, tmat, W1, 128, 64, 128);
    warp_kernel<<<2560,  256, 0, stream>>>(feat2, tmat, W2, 256, 32, 64);

    // 2. offset CNN
    //    conv1 split: ego half (cin 0..63, same for all 4 neighbors of a batch)
    //    computed once per batch into E; neighbor half starts from E.
    conv3x3v2<64, 32, 128, 1, false, false><<<256,  256, 0, stream>>>(W0, w1,            b1, nullptr, nullptr, E);
    conv3x3v2<64, 32, 128, 2, true,  false><<<1024, 256, 0, stream>>>(W0, w1 + 64 * 9,   b1, nullptr, E,       X1);
    stats_kernel<<<512, 256, 0, stream>>>(X1, S, 32768);
    conv3x3v2<32, 16, 32, 0, false, true><<<1024, 256, 0, stream>>>(X1, w2, b2, S, nullptr, X2);
    stats_kernel<<<256, 256, 0, stream>>>(X2, S + 1024, 32768);
    conv1x1_kernel<16, 8><<<2048, 256, 0, stream>>>(X2, w3, b3, S + 1024, X3);
    stats_kernel<<<128, 256, 0, stream>>>(X3, S + 1536, 32768);
    conv1x1_kernel<8, 2><<<2048, 256, 0, stream>>>(X3, w4, b4, S + 1536, G);

    // 3. deform + max fusion per level
    fuse_kernel<<<2048, 256, 0, stream>>>(W0, G, out,            64, 128, 256, 0);
    fuse_kernel<<<1024, 256, 0, stream>>>(W1, G, out + 8388608, 128,  64, 128, 1);
    fuse_kernel<<<512,  256, 0, stream>>>(W2, G, out + 12582912, 256, 32,  64, 2);
}

// Round 3
// 1399.766 us; speedup vs baseline: 1.2632x; 1.0746x over previous
//
#include <hip/hip_runtime.h>

// Problem constants: B=4, N=5, levels (64,128,256),(128,64,128),(256,32,64)

struct Bilin { int i00, i01, i10, i11; float w00, w01, w10, w11; };

__device__ __forceinline__ Bilin make_bilin(float ix, float iy, int W, int H) {
    float x0f = floorf(ix), y0f = floorf(iy);
    float wx1 = ix - x0f, wy1 = iy - y0f;
    float wx0 = 1.f - wx1, wy0 = 1.f - wy1;
    int x0 = (int)x0f, y0 = (int)y0f;
    int x1 = x0 + 1, y1 = y0 + 1;
    bool vx0 = (x0 >= 0 && x0 < W), vx1 = (x1 >= 0 && x1 < W);
    bool vy0 = (y0 >= 0 && y0 < H), vy1 = (y1 >= 0 && y1 < H);
    int cx0 = min(max(x0, 0), W - 1), cx1 = min(max(x1, 0), W - 1);
    int cy0 = min(max(y0, 0), H - 1), cy1 = min(max(y1, 0), H - 1);
    Bilin b;
    b.i00 = cy0 * W + cx0; b.i01 = cy0 * W + cx1;
    b.i10 = cy1 * W + cx0; b.i11 = cy1 * W + cx1;
    b.w00 = (vx0 && vy0) ? wx0 * wy0 : 0.f;
    b.w01 = (vx1 && vy0) ? wx1 * wy0 : 0.f;
    b.w10 = (vx0 && vy1) ? wx0 * wy1 : 0.f;
    b.w11 = (vx1 && vy1) ? wx1 * wy1 : 0.f;
    return b;
}

// Inner sample: warped value at integer px (xq,yq) = affine sample of feat
// (align_corners=True on both the base grid and the sampling).
__device__ __forceinline__ Bilin affine_bilin(const float* th, int xq, int yq, int W, int H) {
    float gx = -1.f + 2.f * xq / (float)(W - 1);
    float gy = -1.f + 2.f * yq / (float)(H - 1);
    float tx = th[0] * gx + th[1] * gy + th[2];
    float ty = th[3] * gx + th[4] * gy + th[5];
    float ix = (tx + 1.f) * 0.5f * (W - 1);
    float iy = (ty + 1.f) * 0.5f * (H - 1);
    return make_bilin(ix, iy, W, H);
}

// Affine warp (align_corners=True), level 0 only. Thread = (img, cg16, h, w).
__global__ __launch_bounds__(256) void warp_kernel(
    const float* __restrict__ src, const float* __restrict__ tmat,
    float* __restrict__ dst, int C, int H, int W)
{
    int idx = blockIdx.x * 256 + threadIdx.x;
    int CGn = C >> 4;
    int HW = H * W;
    int total = 20 * CGn * HW;
    if (idx >= total) return;
    int w   = idx % W;
    int h   = (idx / W) % H;
    int cg  = (idx / HW) % CGn;
    int img = idx / (HW * CGn);
    int b = img / 5, n = img % 5;
    const float* th = tmat + (b * 25 + n) * 6;
    float gx = -1.f + 2.f * w / (float)(W - 1);
    float gy = -1.f + 2.f * h / (float)(H - 1);
    float tx = th[0] * gx + th[1] * gy + th[2];
    float ty = th[3] * gx + th[4] * gy + th[5];
    float ix = (tx + 1.f) * 0.5f * (W - 1);
    float iy = (ty + 1.f) * 0.5f * (H - 1);
    Bilin bl = make_bilin(ix, iy, W, H);
    const float* im = src + ((size_t)img * C + cg * 16) * HW;
    float* op = dst + ((size_t)img * C + cg * 16) * HW + h * W + w;
    #pragma unroll 4
    for (int c = 0; c < 16; ++c) {
        const float* pl = im + c * HW;
        op[c * HW] = pl[bl.i00] * bl.w00 + pl[bl.i01] * bl.w01 +
                     pl[bl.i10] * bl.w10 + pl[bl.i11] * bl.w11;
    }
}

// Zero the stats accumulator region (1792 floats).
__global__ void zero_stats(float* s) {
    for (int i = threadIdx.x; i < 1792; i += 256) s[i] = 0.f;
}

// sums -> (mean, rsqrt(var+eps)) in place. n pairs.
__global__ void finalize_stats(float* s, int n, float inv_hw) {
    int i = threadIdx.x;
    if (i < n) {
        float m = s[2 * i] * inv_hw;
        float v = s[2 * i + 1] * inv_hw - m * m;
        s[2 * i]     = m;
        s[2 * i + 1] = rsqrtf(v + 1e-5f);
    }
}

// Pre-transpose conv weights to [cin][pos][COUT] so the conv kernel can read
// them with wave-uniform (scalar) loads instead of LDS.
__global__ void transpose_w(const float* __restrict__ w1, const float* __restrict__ w2,
                            float* __restrict__ wt1, float* __restrict__ wt2) {
    int t = blockIdx.x * 256 + threadIdx.x;
    for (int i = t; i < 128 * 9 * 32; i += 32 * 256) {
        int o = i % 32, pos = (i / 32) % 9, cin = i / 288;
        wt1[i] = w1[o * 1152 + cin * 9 + pos];
    }
    for (int i = t; i < 32 * 9 * 16; i += 32 * 256) {
        int o = i % 16, pos = (i / 16) % 9, cin = i / 144;
        wt2[i] = w2[o * 288 + cin * 9 + pos];
    }
}

// Direct 3x3 conv v3, pad=1, H=128 W=256.
// Tile 8x64; thread = 8 px x OCP couts. Weights via wave-uniform global loads
// (pre-transposed [cin][pos][COUT]); input staged through LDS with a
// register-prefetch pipeline (load chunk ci+1 while computing ci).
// SRC: 0 plain NCHW; 1 ego (img p<4 -> plane p*5+0); 2 neigh (p<16 -> b*5+1+j).
// INIT: acc += init (ego partials). NORM: IN+leaky on input. STATS: fused
// per-(img,cout) sum/sumsq via wave-reduce + atomicAdd into statacc.
template<int CIN, int COUT, int SRC, bool INIT, bool NORM, bool STATS>
__global__ __launch_bounds__(256, 2) void conv3x3v3(
    const float* __restrict__ src, const float* __restrict__ wt,
    const float* __restrict__ bias, const float* __restrict__ stats,
    const float* __restrict__ init, float* __restrict__ dst,
    float* __restrict__ statacc)
{
    constexpr int H = 128, W = 256, HW = H * W;
    constexpr int CHUNK = 8, NCH = CIN / CHUNK;
    constexpr int OCP = COUT / 4;
    constexpr int PW = 68;
    __shared__ __align__(16) float s_in[CHUNK][10][PW];

    int tid = threadIdx.x, bi = blockIdx.x;
    int p = bi >> 6, rem = bi & 63;
    int h_base = (rem >> 2) * 8;
    int w_base = (rem & 3) * 64;
    int cg = tid >> 6, sg = tid & 63;
    int r = sg >> 3, cw = (sg & 7) * 8;
    int cg_u = __builtin_amdgcn_readfirstlane(cg);

    const float* base;
    if (SRC == 1)      base = src + (size_t)(p * 5) * 64 * HW;
    else if (SRC == 2) { int bb = p >> 2, jm = p & 3; base = src + (size_t)((bb * 5 + 1 + jm) * 64) * HW; }
    else               base = src + (size_t)p * CIN * HW;

    // staging positions: e = tid + k*256 over the 10x66 halo tile (660 slots)
    int gofs[3], lofs[3];
    unsigned pvm = 0, ivm = 0;
    #pragma unroll
    for (int k = 0; k < 3; ++k) {
        int e = tid + k * 256;
        bool pv = (e < 660);
        int row = e / 66, col = e % 66;
        int gy = h_base + row - 1, gx = w_base + col - 1;
        bool iv = pv && gy >= 0 && gy < H && gx >= 0 && gx < W;
        gofs[k] = iv ? (gy * W + gx) : 0;
        lofs[k] = pv ? (row * PW + col) : 0;
        pvm |= (pv ? 1u : 0u) << k;
        ivm |= (iv ? 1u : 0u) << k;
    }
    float* lds = &s_in[0][0][0];

    float acc[OCP][8];
    #pragma unroll
    for (int o = 0; o < OCP; ++o)
        #pragma unroll
        for (int i = 0; i < 8; ++i) acc[o][i] = 0.f;

    float pf[3][CHUNK];
    // prefetch chunk 0
    #pragma unroll
    for (int k = 0; k < 3; ++k)
        if (pvm >> k & 1)
            #pragma unroll
            for (int c = 0; c < CHUNK; ++c)
                pf[k][c] = base[(size_t)c * HW + gofs[k]];

    for (int ci = 0; ci < NCH; ++ci) {
        if (ci) __syncthreads();
        // store prefetched chunk to LDS (apply IN+leaky here if NORM)
        float mrs[NORM ? 2 * CHUNK : 1];
        if (NORM) {
            const float4* sp = (const float4*)(stats + (size_t)(p * CIN + ci * CHUNK) * 2);
            #pragma unroll
            for (int q = 0; q < CHUNK / 2; ++q) {
                float4 v = sp[q];
                mrs[q * 4] = v.x; mrs[q * 4 + 1] = v.y; mrs[q * 4 + 2] = v.z; mrs[q * 4 + 3] = v.w;
            }
        }
        #pragma unroll
        for (int k = 0; k < 3; ++k) {
            if (pvm >> k & 1) {
                #pragma unroll
                for (int c = 0; c < CHUNK; ++c) {
                    float v = (ivm >> k & 1) ? pf[k][c] : 0.f;
                    if (NORM && (ivm >> k & 1)) {
                        v = (v - mrs[2 * c]) * mrs[2 * c + 1];
                        v = v >= 0.f ? v : 0.01f * v;
                    }
                    lds[c * (10 * PW) + lofs[k]] = v;
                }
            }
        }
        __syncthreads();
        // prefetch next chunk
        if (ci + 1 < NCH) {
            const float* nb = base + (size_t)(ci + 1) * CHUNK * HW;
            #pragma unroll
            for (int k = 0; k < 3; ++k)
                if (pvm >> k & 1)
                    #pragma unroll
                    for (int c = 0; c < CHUNK; ++c)
                        pf[k][c] = nb[(size_t)c * HW + gofs[k]];
        }
        // compute chunk ci
        #pragma unroll 1
        for (int c = 0; c < CHUNK; ++c) {
            float in[3][10];
            #pragma unroll
            for (int dy = 0; dy < 3; ++dy) {
                const float* rp = &s_in[c][r + dy][cw];
                float4 a = *reinterpret_cast<const float4*>(rp);
                float4 b = *reinterpret_cast<const float4*>(rp + 4);
                float2 e = *reinterpret_cast<const float2*>(rp + 8);
                in[dy][0] = a.x; in[dy][1] = a.y; in[dy][2] = a.z; in[dy][3] = a.w;
                in[dy][4] = b.x; in[dy][5] = b.y; in[dy][6] = b.z; in[dy][7] = b.w;
                in[dy][8] = e.x; in[dy][9] = e.y;
            }
            const float* wp = wt + (size_t)((ci * CHUNK + c) * 9) * COUT + cg_u * OCP;
            #pragma unroll
            for (int pos = 0; pos < 9; ++pos) {
                const int dy = pos / 3, dx = pos % 3;
                float wv[OCP];
                #pragma unroll
                for (int oq = 0; oq < OCP; oq += 4) {
                    float4 wq = *reinterpret_cast<const float4*>(wp + pos * COUT + oq);
                    wv[oq] = wq.x; wv[oq + 1] = wq.y; wv[oq + 2] = wq.z; wv[oq + 3] = wq.w;
                }
                #pragma unroll
                for (int o = 0; o < OCP; ++o)
                    #pragma unroll
                    for (int px = 0; px < 8; ++px)
                        acc[o][px] = fmaf(in[dy][dx + px], wv[o], acc[o][px]);
            }
        }
    }
    // epilogue
    int hh = h_base + r, ww = w_base + cw;
    #pragma unroll
    for (int o = 0; o < OCP; ++o) {
        int oc = cg * OCP + o;
        float bv = (SRC == 1) ? 0.f : bias[oc];
        float add[8];
        #pragma unroll
        for (int i = 0; i < 8; ++i) add[i] = bv;
        if (INIT) {
            int bb = (SRC == 2) ? (p >> 2) : p;
            const float* ip = init + ((size_t)bb * COUT + oc) * HW + hh * W + ww;
            float4 e0 = *reinterpret_cast<const float4*>(ip);
            float4 e1 = *reinterpret_cast<const float4*>(ip + 4);
            add[0] += e0.x; add[1] += e0.y; add[2] += e0.z; add[3] += e0.w;
            add[4] += e1.x; add[5] += e1.y; add[6] += e1.z; add[7] += e1.w;
        }
        float vals[8];
        #pragma unroll
        for (int i = 0; i < 8; ++i) vals[i] = acc[o][i] + add[i];
        float* op = dst + (((size_t)p * COUT + oc) * H + hh) * W + ww;
        *reinterpret_cast<float4*>(op)     = make_float4(vals[0], vals[1], vals[2], vals[3]);
        *reinterpret_cast<float4*>(op + 4) = make_float4(vals[4], vals[5], vals[6], vals[7]);
        if (STATS) {
            float s = 0.f, s2 = 0.f;
            #pragma unroll
            for (int i = 0; i < 8; ++i) { s += vals[i]; s2 += vals[i] * vals[i]; }
            #pragma unroll
            for (int off = 32; off > 0; off >>= 1) {
                s  += __shfl_down(s, off);
                s2 += __shfl_down(s2, off);
            }
            if (sg == 0) {
                atomicAdd(&statacc[(size_t)(p * COUT + oc) * 2],     s);
                atomicAdd(&statacc[(size_t)(p * COUT + oc) * 2 + 1], s2);
            }
        }
    }
}

// 1x1 conv with fused IN+leaky on input; optional fused stats on output.
template<int CIN, int COUT, bool STATS>
__global__ __launch_bounds__(256) void conv1x1_kernel(
    const float* __restrict__ src, const float* __restrict__ wgt,
    const float* __restrict__ bias, const float* __restrict__ stats,
    float* __restrict__ dst, float* __restrict__ statacc)
{
    constexpr int HW = 128 * 256;
    __shared__ float s_w[COUT * CIN];
    __shared__ float s_b[COUT];
    __shared__ float s_part[4][2 * COUT];
    int tid = threadIdx.x;
    for (int t = tid; t < COUT * CIN; t += 256) s_w[t] = wgt[t];
    if (tid < COUT) s_b[tid] = bias[tid];
    __syncthreads();
    int p  = blockIdx.x >> 7;
    int px = ((blockIdx.x & 127) << 8) + tid;
    float in[CIN];
    #pragma unroll
    for (int c = 0; c < CIN; ++c) {
        float v  = src[((size_t)p * CIN + c) * HW + px];
        float m  = stats[(p * CIN + c) * 2];
        float rs = stats[(p * CIN + c) * 2 + 1];
        v = (v - m) * rs;
        in[c] = v >= 0.f ? v : 0.01f * v;
    }
    float val[COUT];
    #pragma unroll
    for (int o = 0; o < COUT; ++o) {
        float s = s_b[o];
        #pragma unroll
        for (int c = 0; c < CIN; ++c) s = fmaf(in[c], s_w[o * CIN + c], s);
        val[o] = s;
        dst[((size_t)p * COUT + o) * HW + px] = s;
    }
    if (STATS) {
        int wv = tid >> 6, ln = tid & 63;
        #pragma unroll
        for (int o = 0; o < COUT; ++o) {
            float s = val[o], s2 = val[o] * val[o];
            #pragma unroll
            for (int off = 32; off > 0; off >>= 1) {
                s  += __shfl_down(s, off);
                s2 += __shfl_down(s2, off);
            }
            if (ln == 0) { s_part[wv][o * 2] = s; s_part[wv][o * 2 + 1] = s2; }
        }
        __syncthreads();
        if (tid < 2 * COUT) {
            float t = s_part[0][tid] + s_part[1][tid] + s_part[2][tid] + s_part[3][tid];
            atomicAdd(&statacc[(size_t)p * COUT * 2 + tid], t);
        }
    }
}

// Level-0 fusion: deform-sample 4 neighbors from W0 + max with ego plane.
// Thread = (b, cg32, h, w), 32 channels.
__global__ __launch_bounds__(256) void fuse0_kernel(
    const float* __restrict__ W0, const float* __restrict__ grid,
    float* __restrict__ out)
{
    constexpr int HW = 32768;
    int idx = blockIdx.x * 256 + threadIdx.x;   // 4 * 2 * 32768
    int px = idx & 32767;
    int cg = (idx >> 15) & 1;
    int b  = idx >> 16;
    int w = px & 255, h = px >> 8;
    float bx = (w + 0.5f) * (2.f / 256.f) - 1.f;
    float by = (h + 0.5f) * (2.f / 128.f) - 1.f;
    Bilin bl[4];
    #pragma unroll
    for (int j = 0; j < 4; ++j) {
        const float2 g = *reinterpret_cast<const float2*>(
            grid + ((size_t)(b * 4 + j)) * 65536 + (size_t)px * 2);
        float ix = ((g.x + bx + 1.f) * 256.f - 1.f) * 0.5f;
        float iy = ((g.y + by + 1.f) * 128.f - 1.f) * 0.5f;
        bl[j] = make_bilin(ix, iy, 256, 128);
    }
    const float* ego = W0 + ((size_t)(b * 5) * 64 + cg * 32) * HW + px;
    float* op = out + ((size_t)b * 64 + cg * 32) * HW + px;
    #pragma unroll 2
    for (int c = 0; c < 32; ++c) {
        float mx = ego[(size_t)c * HW];
        #pragma unroll
        for (int j = 0; j < 4; ++j) {
            const float* pl = W0 + ((size_t)(b * 5 + 1 + j) * 64 + cg * 32 + c) * HW;
            float s = pl[bl[j].i00] * bl[j].w00 + pl[bl[j].i01] * bl[j].w01 +
                      pl[bl[j].i10] * bl[j].w10 + pl[bl[j].i11] * bl[j].w11;
            mx = fmaxf(mx, s);
        }
        op[(size_t)c * HW] = mx;
    }
}

// Levels 1,2 fusion, composed: no materialized warp. Ego = inline affine
// sample; neighbor = outer bilinear (align_corners=False) over warped px,
// each warped px = inner affine bilinear of feat — 16 reads with
// premultiplied weights. Exact modulo fp association.
template<int C, int CPT, int SH, int HS, int WS>
__global__ __launch_bounds__(256) void fuse_comp(
    const float* __restrict__ feat, const float* __restrict__ tmat,
    const float* __restrict__ grid, float* __restrict__ out)
{
    constexpr int HW = HS * WS;
    constexpr int NCG = C / CPT;
    int idx = blockIdx.x * 256 + threadIdx.x;
    if (idx >= 4 * NCG * HW) return;
    int px = idx % HW;
    int cg = (idx / HW) % NCG;
    int b  = idx / (HW * NCG);
    int w = px % WS, h = px / WS;

    float m[CPT];
    {   // ego
        const float* th = tmat + (size_t)(b * 25) * 6;
        float t0 = th[0], t1 = th[1], t2 = th[2], t3 = th[3], t4 = th[4], t5 = th[5];
        float thr[6] = {t0, t1, t2, t3, t4, t5};
        Bilin bi = affine_bilin(thr, w, h, WS, HS);
        const float* pb = feat + ((size_t)(b * 5) * C + cg * CPT) * HW;
        #pragma unroll 4
        for (int c = 0; c < CPT; ++c) {
            const float* pl = pb + (size_t)c * HW;
            m[c] = pl[bi.i00] * bi.w00 + pl[bi.i01] * bi.w01 +
                   pl[bi.i10] * bi.w10 + pl[bi.i11] * bi.w11;
        }
    }
    int h0 = h << SH, w0 = w << SH;
    float bx = (w0 + 0.5f) * (2.f / 256.f) - 1.f;
    float by = (h0 + 0.5f) * (2.f / 128.f) - 1.f;
    for (int j = 0; j < 4; ++j) {
        const float2 g = *reinterpret_cast<const float2*>(
            grid + ((size_t)(b * 4 + j)) * 65536 + (size_t)(h0 * 256 + w0) * 2);
        float ix = ((g.x + bx + 1.f) * WS - 1.f) * 0.5f;
        float iy = ((g.y + by + 1.f) * HS - 1.f) * 0.5f;
        // outer corners
        float x0f = floorf(ix), y0f = floorf(iy);
        float wx1 = ix - x0f, wy1 = iy - y0f;
        float wx0 = 1.f - wx1, wy0 = 1.f - wy1;
        int x0 = (int)x0f, y0 = (int)y0f, x1 = x0 + 1, y1 = y0 + 1;
        bool vx0 = (x0 >= 0 && x0 < WS), vx1 = (x1 >= 0 && x1 < WS);
        bool vy0 = (y0 >= 0 && y0 < HS), vy1 = (y1 >= 0 && y1 < HS);
        int cx0 = min(max(x0, 0), WS - 1), cx1 = min(max(x1, 0), WS - 1);
        int cy0 = min(max(y0, 0), HS - 1), cy1 = min(max(y1, 0), HS - 1);
        float ow[4] = { (vx0 && vy0) ? wx0 * wy0 : 0.f,
                        (vx1 && vy0) ? wx1 * wy0 : 0.f,
                        (vx0 && vy1) ? wx0 * wy1 : 0.f,
                        (vx1 && vy1) ? wx1 * wy1 : 0.f };
        int qx[4] = { cx0, cx1, cx0, cx1 };
        int qy[4] = { cy0, cy0, cy1, cy1 };
        const float* th = tmat + (size_t)(b * 25 + 1 + j) * 6;
        float thr[6] = { th[0], th[1], th[2], th[3], th[4], th[5] };
        Bilin in_[4];
        #pragma unroll
        for (int q = 0; q < 4; ++q) {
            in_[q] = affine_bilin(thr, qx[q], qy[q], WS, HS);
            in_[q].w00 *= ow[q]; in_[q].w01 *= ow[q];
            in_[q].w10 *= ow[q]; in_[q].w11 *= ow[q];
        }
        const float* pb = feat + ((size_t)(b * 5 + 1 + j) * C + cg * CPT) * HW;
        #pragma unroll 2
        for (int c = 0; c < CPT; ++c) {
            const float* pl = pb + (size_t)c * HW;
            float s = 0.f;
            #pragma unroll
            for (int q = 0; q < 4; ++q)
                s += pl[in_[q].i00] * in_[q].w00 + pl[in_[q].i01] * in_[q].w01 +
                     pl[in_[q].i10] * in_[q].w10 + pl[in_[q].i11] * in_[q].w11;
            m[c] = fmaxf(m[c], s);
        }
    }
    float* op = out + ((size_t)b * C + cg * CPT) * HW + px;
    #pragma unroll
    for (int c = 0; c < CPT; ++c) op[(size_t)c * HW] = m[c];
}

extern "C" void kernel_launch(void* const* d_in, const int* in_sizes, int n_in,
                              void* d_out, int out_size, void* d_ws, size_t ws_size,
                              hipStream_t stream)
{
    const float* feat0 = (const float*)d_in[0];
    const float* feat1 = (const float*)d_in[1];
    const float* feat2 = (const float*)d_in[2];
    const float* tmat  = (const float*)d_in[3];
    const float* w1 = (const float*)d_in[5];
    const float* b1 = (const float*)d_in[6];
    const float* w2 = (const float*)d_in[7];
    const float* b2 = (const float*)d_in[8];
    const float* w3 = (const float*)d_in[9];
    const float* b3 = (const float*)d_in[10];
    const float* w4 = (const float*)d_in[11];
    const float* b4 = (const float*)d_in[12];
    float* out = (float*)d_out;
    float* ws  = (float*)d_ws;

    // workspace layout (floats)
    const size_t nW0 = 41943040;  // 20*64*128*256
    const size_t nX1 = 16777216;  // 16*32*128*256
    const size_t nX2 = 8388608;   // 16*16*128*256
    const size_t nX3 = 4194304;   // 16*8*128*256
    const size_t nG  = 2097152;   // 16*2*128*256
    const size_t nS  = 2048;
    const size_t nWT = 36864 + 4608;
    const size_t needed = (nW0 + nX1 + nX2 + nX3 + nG + nS + nWT) * 4;
    if (ws_size < needed) return;

    float* W0  = ws;
    float* X1  = W0 + nW0;
    float* X2  = X1 + nX1;
    float* X3  = X2 + nX2;
    float* G   = X3 + nX3;
    float* S   = G  + nG;    // stats sums: X1@0(1024), X2@1024(512), X3@1536(256)
    float* WT1 = S  + nS;
    float* WT2 = WT1 + 36864;
    float* E   = X2;         // ego partials (4*32*32768) overlay X2 (dead until conv2)

    zero_stats<<<1, 256, 0, stream>>>(S);
    transpose_w<<<32, 256, 0, stream>>>(w1, w2, WT1, WT2);

    // level-0 affine warp (needed by conv1 and fuse0)
    warp_kernel<<<10240, 256, 0, stream>>>(feat0, tmat, W0, 64, 128, 256);

    // offset CNN: conv1 split into ego (once per batch) + neighbor (+init)
    conv3x3v3<64, 32, 1, false, false, false><<<256,  256, 0, stream>>>(W0, WT1, b1, nullptr, nullptr, E, nullptr);
    conv3x3v3<64, 32, 2, true,  false, true ><<<1024, 256, 0, stream>>>(W0, WT1 + 8 * 8 * 9 * 32, b1, nullptr, E, X1, S);
    finalize_stats<<<1, 512, 0, stream>>>(S, 512, 1.f / 32768.f);
    conv3x3v3<32, 16, 0, false, true,  true ><<<1024, 256, 0, stream>>>(X1, WT2, b2, S, nullptr, X2, S + 1024);
    finalize_stats<<<1, 256, 0, stream>>>(S + 1024, 256, 1.f / 32768.f);
    conv1x1_kernel<16, 8, true ><<<2048, 256, 0, stream>>>(X2, w3, b3, S + 1024, X3, S + 1536);
    finalize_stats<<<1, 128, 0, stream>>>(S + 1536, 128, 1.f / 32768.f);
    conv1x1_kernel<8, 2, false><<<2048, 256, 0, stream>>>(X3, w4, b4, S + 1536, G, nullptr);

    // fusion
    fuse0_kernel<<<1024, 256, 0, stream>>>(W0, G, out);
    fuse_comp<128, 32, 1, 64, 128><<<512, 256, 0, stream>>>(feat1, tmat, G, out + 8388608);
    fuse_comp<256, 16, 2, 32,  64><<<512, 256, 0, stream>>>(feat2, tmat, G, out + 12582912);
}